// Round 12
// baseline (266.327 us; speedup 1.0000x reference)
//
#include <hip/hip_runtime.h>
#include <hip/hip_bf16.h>

// Dense FFN: out = relu(x @ w1 + b1) @ w2 + b2
// x  [8192,1024] f32, w1 [1024,4096] f32, b1 [4096] f32,
// w2 [4096,1024] f32, b2 [1024] f32, out [8192,1024] f32.
//
// R12: GEMM1 = R11's verified 3-ring counted-vmcnt pipeline + PHASE BARRIERS
//   (T3 given T4).  R11 (T4 alone, no barriers) was exactly neutral -- as
//   m218's matrix predicts; R3 (T3+T4 + sched_barrier(0) + manual lgkmcnt
//   pins) regressed -- m141 attributes -42% to the pin alone.  This round
//   tests the untested clean cell: per phase {ds_reads || gloads -> raw
//   s_barrier -> setprio(1) -> 16 MFMA -> setprio(0) -> raw s_barrier},
//   counted vmcnt(6) once per K-tile, compiler-placed lgkm waits, no pins.
//   Raw barriers are safe: ds_reads hit only the cur buffer (published a
//   full barrier-generation ago); gloads hit a buffer unread for 2 more
//   generations; the ring/vmcnt algebra is R11-verified (passed).
//   GEMM2 (128x128/BK=128, 81.8us, 0 conflicts) and prep bit-identical R9/R6.

typedef __bf16 bf16;
typedef __bf16 bf16x4 __attribute__((ext_vector_type(4)));
typedef __bf16 bf16x8 __attribute__((ext_vector_type(8)));
typedef float  f32x4  __attribute__((ext_vector_type(4)));

#define G1_ASZ (256 * 64)
#define G1_BSZ (128 * 64)

__device__ __forceinline__ void gload_lds16(const bf16* g, bf16* l) {
    __builtin_amdgcn_global_load_lds(
        (const __attribute__((address_space(1))) unsigned int*)g,
        (__attribute__((address_space(3))) unsigned int*)l,
        16, 0, 0);
}

// ---------------------------------------------------------------------------
// fused prep: [0,8192) cast x->bf16; [8192,9216) w1 transpose;
//             [9216,10240) w2 transpose.  (R6-verified)
__device__ __forceinline__ void transpose_tile(
    const float* __restrict__ in, bf16* __restrict__ out,
    int K, int N, int k0, int n0, int t, bf16 (*tile)[72])
{
    const int lr = t >> 4;
    const int lc = (t & 15) << 2;
#pragma unroll
    for (int p = 0; p < 4; ++p) {
        int k = p * 16 + lr;
        float4 v = *(const float4*)(in + (size_t)(k0 + k) * N + n0 + lc);
        tile[lc + 0][k] = (bf16)v.x;
        tile[lc + 1][k] = (bf16)v.y;
        tile[lc + 2][k] = (bf16)v.z;
        tile[lc + 3][k] = (bf16)v.w;
    }
    __syncthreads();

    const int wr = t >> 3;
    const int wc = (t & 7) << 3;
#pragma unroll
    for (int p = 0; p < 2; ++p) {
        int n = p * 32 + wr;
        *(bf16x8*)(out + (size_t)(n0 + n) * K + k0 + wc) =
            *(const bf16x8*)&tile[n][wc];
    }
}

__global__ __launch_bounds__(256) void prep_fused(
    const float* __restrict__ x,  bf16* __restrict__ xb,
    const float* __restrict__ w1, bf16* __restrict__ w1t,
    const float* __restrict__ w2, bf16* __restrict__ w2t)
{
    __shared__ __align__(16) bf16 tile[64][72];
    const int bid = blockIdx.x;
    const int t   = threadIdx.x;

    if (bid < 8192) {
        int i = bid * 256 + t;
        float4 v = ((const float4*)x)[i];
        bf16x4 o;
        o.x = (bf16)v.x; o.y = (bf16)v.y; o.z = (bf16)v.z; o.w = (bf16)v.w;
        ((bf16x4*)xb)[i] = o;
    } else if (bid < 9216) {
        int b = bid - 8192;
        transpose_tile(w1, w1t, 1024, 4096, (b >> 6) * 64, (b & 63) * 64, t, tile);
    } else {
        int b = bid - 9216;
        transpose_tile(w2, w2t, 4096, 1024, (b >> 4) * 64, (b & 15) * 64, t, tile);
    }
}

// ---------------------------------------------------------------------------
// GEMM1: h = relu(A @ Bt^T + bias), bf16 out.  A=[M][K] xb, Bt=[N][K] w1t.
// 256x128 tile, BK=64, 512 thr (8 waves 2Mx4N, 128x32/wave), LDS 144 KiB,
// 3-ring counted-vmcnt schedule + per-phase raw barriers (T3+T4+T5 clean).
__global__ __launch_bounds__(512, 1) void gemm1_pipe(
    const bf16* __restrict__ A, const bf16* __restrict__ Bt,
    const float* __restrict__ bias, bf16* __restrict__ Cb,
    int M, int N, int K)
{
    __shared__ __align__(16) bf16 As[3 * G1_ASZ];   // 96 KiB
    __shared__ __align__(16) bf16 Bs[3 * G1_BSZ];   // 48 KiB

    const int tid  = threadIdx.x;
    const int wave = tid >> 6;
    const int lane = tid & 63;
    const int tx   = blockIdx.x;      // N-tile (128)
    const int ty   = blockIdx.y;      // M-tile (256)
    const size_t K_ = (size_t)K;

    // staging: one round = 512 thr x 16B = 64 rows x 64 elems.
    // row in round = tid>>3, chunk slot = tid&7, global chunk = slot^(row&7).
    const int srow = tid >> 3;                       // 0..63
    const int swc  = ((tid & 7) ^ (srow & 7)) << 3;  // elem offset
    const bf16* gA[4]; const bf16* gB[2];
#pragma unroll
    for (int g = 0; g < 4; ++g)
        gA[g] = A + ((size_t)ty * 256 + g * 64 + srow) * K_ + swc;
#pragma unroll
    for (int g = 0; g < 2; ++g)
        gB[g] = Bt + ((size_t)tx * 128 + g * 64 + srow) * K_ + swc;
    const int ldsOff = tid * 8;       // linear dest within buffer (+g*4096)

    const int wm   = (wave >> 2) * 128;   // 0,128
    const int wn   = (wave & 3) * 32;     // 0,32,64,96
    const int quad = lane >> 4;
    const int r    = lane & 15;
    const int r7   = lane & 7;

    f32x4 acc[8][2] = {};
    const int NT = K >> 6;            // 16

    // ---- prologue: stage tiles 0 (buf0) and 1 (buf1) ----
#pragma unroll
    for (int g = 0; g < 4; ++g) { gload_lds16(gA[g], &As[0 * G1_ASZ + g * 4096 + ldsOff]); gA[g] += 64; }
#pragma unroll
    for (int g = 0; g < 2; ++g) { gload_lds16(gB[g], &Bs[0 * G1_BSZ + g * 4096 + ldsOff]); gB[g] += 64; }
#pragma unroll
    for (int g = 0; g < 4; ++g) { gload_lds16(gA[g], &As[1 * G1_ASZ + g * 4096 + ldsOff]); gA[g] += 64; }
#pragma unroll
    for (int g = 0; g < 2; ++g) { gload_lds16(gB[g], &Bs[1 * G1_BSZ + g * 4096 + ldsOff]); gB[g] += 64; }
    asm volatile("s_waitcnt vmcnt(6)" ::: "memory");   // tile 0 landed
    __builtin_amdgcn_s_barrier();
    asm volatile("" ::: "memory");

    int cur = 0;
    for (int t = 0; t < NT; ++t) {
        const int nb = (cur + 2 >= 3) ? cur - 1 : cur + 2;   // (t+2)%3
        const bf16* Ac = &As[cur * G1_ASZ];
        const bf16* Bc = &Bs[cur * G1_BSZ];
        bf16* An = &As[nb * G1_ASZ];
        bf16* Bn = &Bs[nb * G1_BSZ];
        const bool st = (t + 2 < NT);

        // ===== phase 0: A-half0 + B frags (12 ds_read); 3 gloads; 16 MFMA ==
        bf16x8 af[4][2], bfr[2][2];
#pragma unroll
        for (int i = 0; i < 4; ++i)
#pragma unroll
            for (int h = 0; h < 2; ++h)
                af[i][h] = *(const bf16x8*)&Ac[(wm + i * 16 + r) * 64 +
                                               (((h * 4 + quad) ^ r7) << 3)];
#pragma unroll
        for (int j = 0; j < 2; ++j)
#pragma unroll
            for (int h = 0; h < 2; ++h)
                bfr[j][h] = *(const bf16x8*)&Bc[(wn + j * 16 + r) * 64 +
                                                (((h * 4 + quad) ^ r7) << 3)];
        if (st) {
            gload_lds16(gA[0], An + 0 * 4096 + ldsOff);
            gload_lds16(gA[1], An + 1 * 4096 + ldsOff);
            gload_lds16(gA[2], An + 2 * 4096 + ldsOff);
        }
        __builtin_amdgcn_s_barrier();          // phase gate (raw; no drain)
        __builtin_amdgcn_s_setprio(1);
#pragma unroll
        for (int i = 0; i < 4; ++i)
#pragma unroll
            for (int j = 0; j < 2; ++j) {
                acc[i][j] = __builtin_amdgcn_mfma_f32_16x16x32_bf16(
                    af[i][0], bfr[j][0], acc[i][j], 0, 0, 0);
                acc[i][j] = __builtin_amdgcn_mfma_f32_16x16x32_bf16(
                    af[i][1], bfr[j][1], acc[i][j], 0, 0, 0);
            }
        __builtin_amdgcn_s_setprio(0);
        __builtin_amdgcn_s_barrier();          // phase gate

        // ===== phase 1: A-half1 frags (8 ds_read); 3 gloads; 16 MFMA =======
        bf16x8 ag[4][2];
#pragma unroll
        for (int i = 0; i < 4; ++i)
#pragma unroll
            for (int h = 0; h < 2; ++h)
                ag[i][h] = *(const bf16x8*)&Ac[(wm + 64 + i * 16 + r) * 64 +
                                               (((h * 4 + quad) ^ r7) << 3)];
        if (st) {
            gload_lds16(gA[3], An + 3 * 4096 + ldsOff);
            gload_lds16(gB[0], Bn + 0 * 4096 + ldsOff);
            gload_lds16(gB[1], Bn + 1 * 4096 + ldsOff);
#pragma unroll
            for (int g = 0; g < 4; ++g) gA[g] += 64;
#pragma unroll
            for (int g = 0; g < 2; ++g) gB[g] += 64;
        }
        __builtin_amdgcn_s_barrier();          // phase gate
        __builtin_amdgcn_s_setprio(1);
#pragma unroll
        for (int i = 0; i < 4; ++i)
#pragma unroll
            for (int j = 0; j < 2; ++j) {
                acc[i + 4][j] = __builtin_amdgcn_mfma_f32_16x16x32_bf16(
                    ag[i][0], bfr[j][0], acc[i + 4][j], 0, 0, 0);
                acc[i + 4][j] = __builtin_amdgcn_mfma_f32_16x16x32_bf16(
                    ag[i][1], bfr[j][1], acc[i + 4][j], 0, 0, 0);
            }
        __builtin_amdgcn_s_setprio(0);

        // ===== K-tile boundary: counted drain + publishing barrier =========
        if (st) { asm volatile("s_waitcnt vmcnt(6)" ::: "memory"); }
        else    { asm volatile("s_waitcnt vmcnt(0)" ::: "memory"); }
        __builtin_amdgcn_s_barrier();
        asm volatile("" ::: "memory");

        cur = (cur == 2) ? 0 : cur + 1;
    }

    // epilogue: C/D col = lane&15, row = quad*4 + reg
    const int m_base = ty * 256 + wm + quad * 4;
    const int n_base = tx * 128 + wn + r;
    float bv[2];
#pragma unroll
    for (int j = 0; j < 2; ++j) bv[j] = bias[n_base + j * 16];

#pragma unroll
    for (int i = 0; i < 8; ++i) {
#pragma unroll
        for (int p = 0; p < 4; ++p) {
            size_t row = (size_t)(m_base + i * 16 + p) * (size_t)N;
#pragma unroll
            for (int j = 0; j < 2; ++j) {
                float v = acc[i][j][p] + bv[j];
                v = v > 0.f ? v : 0.f;
                Cb[row + n_base + j * 16] = (bf16)v;
            }
        }
    }
}

// ---------------------------------------------------------------------------
// GEMM2: out = A @ Bt^T + bias, f32 out.  Bit-identical R9 body:
// 128x128 tile, BK=128, 256 thr, 32 K-iters, LDS 64 KiB (2 blocks/CU),
// 16-chunk XOR swizzle mask &15 (verified 0 conflicts, 81.8 us).
__global__ __launch_bounds__(256, 2) void gemm_bt2_k128(
    const bf16* __restrict__ A, const bf16* __restrict__ Bt,
    const float* __restrict__ bias, float* __restrict__ Cf,
    int M, int N, int K)
{
    __shared__ __align__(16) bf16 As[128 * 128];   // 32 KiB
    __shared__ __align__(16) bf16 Bs[128 * 128];   // 32 KiB

    const int tid  = threadIdx.x;
    const int wave = tid >> 6;
    const int lane = tid & 63;

    const int sr   = tid >> 4;                     // 0..15
    const int swc  = ((tid & 15) ^ sr) << 3;       // elem offset of 16B chunk
    const size_t K_ = (size_t)K;

    const bf16* gA[8]; const bf16* gB[8];
    bf16* lA[8]; bf16* lB[8];
#pragma unroll
    for (int g = 0; g < 8; ++g) {
        const int rr = g * 16 + sr;
        gA[g] = A  + ((size_t)blockIdx.y * 128 + rr) * K_ + swc;
        gB[g] = Bt + ((size_t)blockIdx.x * 128 + rr) * K_ + swc;
        lA[g] = &As[(g * 16) * 128] + tid * 8;     // linear dest
        lB[g] = &Bs[(g * 16) * 128] + tid * 8;
    }

    const int wm   = (wave >> 1) << 6;
    const int wn   = (wave & 1) << 6;
    const int quad = lane >> 4;
    const int r    = lane & 15;

    f32x4 acc[4][4] = {};

    for (int k0 = 0; k0 < K; k0 += 128) {
        __syncthreads();
#pragma unroll
        for (int g = 0; g < 8; ++g) {
            gload_lds16(gA[g], lA[g]);
            gload_lds16(gB[g], lB[g]);
            gA[g] += 128; gB[g] += 128;
        }
        __syncthreads();

#pragma unroll
        for (int ks = 0; ks < 4; ++ks) {           // 4 k-sub-steps of 32
            bf16x8 af[4], bfr[4];
#pragma unroll
            for (int i = 0; i < 4; ++i) {
                const int row = wm + i * 16 + r;
                const int ch  = (((ks * 4 + quad) ^ (row & 15)) << 3);
                af[i] = *(const bf16x8*)&As[row * 128 + ch];
            }
#pragma unroll
            for (int j = 0; j < 4; ++j) {
                const int row = wn + j * 16 + r;
                const int ch  = (((ks * 4 + quad) ^ (row & 15)) << 3);
                bfr[j] = *(const bf16x8*)&Bs[row * 128 + ch];
            }
#pragma unroll
            for (int i = 0; i < 4; ++i)
#pragma unroll
                for (int j = 0; j < 4; ++j)
                    acc[i][j] = __builtin_amdgcn_mfma_f32_16x16x32_bf16(
                        af[i], bfr[j], acc[i][j], 0, 0, 0);
        }
    }

    const int m_base = blockIdx.y * 128 + wm + quad * 4;
    const int n_base = blockIdx.x * 128 + wn + r;
    float bv[4];
#pragma unroll
    for (int j = 0; j < 4; ++j) bv[j] = bias[n_base + j * 16];

#pragma unroll
    for (int i = 0; i < 4; ++i) {
#pragma unroll
        for (int p = 0; p < 4; ++p) {
            size_t row = (size_t)(m_base + i * 16 + p) * (size_t)N;
#pragma unroll
            for (int j = 0; j < 4; ++j) {
                Cf[row + n_base + j * 16] = acc[i][j][p] + bv[j];
            }
        }
    }
}

// ---------------------------------------------------------------------------
extern "C" void kernel_launch(void* const* d_in, const int* in_sizes, int n_in,
                              void* d_out, int out_size, void* d_ws, size_t ws_size,
                              hipStream_t stream)
{
    const float* x  = (const float*)d_in[0];  // [8192,1024]
    const float* w1 = (const float*)d_in[1];  // [1024,4096]
    const float* b1 = (const float*)d_in[2];  // [4096]
    const float* w2 = (const float*)d_in[3];  // [4096,1024]
    const float* b2 = (const float*)d_in[4];  // [1024]
    float* out = (float*)d_out;               // [8192,1024]

    const int M = 8192, D = 1024, W = 4096;

    char* ws = (char*)d_ws;
    bf16* xb  = (bf16*)(ws);                           // 16 MiB: [8192,1024]
    bf16* w1t = (bf16*)(ws + (size_t)(16 << 20));      //  8 MiB: [4096,1024]
    bf16* w2t = (bf16*)(ws + (size_t)(24 << 20));      //  8 MiB: [1024,4096]
    bf16* h   = (bf16*)(ws + (size_t)(32 << 20));      // 64 MiB: [8192,4096]

    // 1. fused prep: cast x + transpose w1 + transpose w2 (one launch)
    prep_fused<<<10240, 256, 0, stream>>>(x, xb, w1, w1t, w2, w2t);

    // 2. h = relu(xb @ w1 + b1), bf16  [M][W]   256x128 tile, phased pipeline
    gemm1_pipe<<<dim3(W / 128, M / 256), 512, 0, stream>>>(
        xb, w1t, b1, h, M, W, D);

    // 3. out = h @ w2 + b2, f32  [M][D]         128x128 tile, BK=128
    gemm_bt2_k128<<<dim3(D / 128, M / 128), 256, 0, stream>>>(
        h, w2t, b2, out, M, D, W);
}

// Round 13
// 250.488 us; speedup vs baseline: 1.0632x; 1.0632x over previous
//
#include <hip/hip_runtime.h>
#include <hip/hip_bf16.h>

// Dense FFN: out = relu(x @ w1 + b1) @ w2 + b2
// x  [8192,1024] f32, w1 [1024,4096] f32, b1 [4096] f32,
// w2 [4096,1024] f32, b2 [1024] f32, out [8192,1024] f32.
//
// R13 = exact revert to the verified-best component set (R9, 248.3 us;
// statistically tied with R6's 247.7):
//   prep_fused: cast x + transpose w1 + transpose w2, one launch (R6, -17us)
//   GEMM1: 128x128, BK=64, 256 thr, chunk-XOR swizzle &7 (85.0 us, 0 confl)
//   GEMM2: 128x128, BK=128, 256 thr, 16-chunk swizzle &15 (81.8 us, 0 confl)
// Structural edits R3/R4/R5/R7/R10/R11/R12 all measured negative or neutral;
// both GEMMs are at the documented m97-structure shape ceiling (stall-bound:
// L3-warm dispatches at 410 GB/s run identical 82 us).

typedef __bf16 bf16;
typedef __bf16 bf16x4 __attribute__((ext_vector_type(4)));
typedef __bf16 bf16x8 __attribute__((ext_vector_type(8)));
typedef float  f32x4  __attribute__((ext_vector_type(4)));

#define BM 128
#define BN 128
#define BK 64

__device__ __forceinline__ void gload_lds16(const bf16* g, bf16* l) {
    __builtin_amdgcn_global_load_lds(
        (const __attribute__((address_space(1))) unsigned int*)g,
        (__attribute__((address_space(3))) unsigned int*)l,
        16, 0, 0);
}

// ---------------------------------------------------------------------------
// fused prep: [0,8192) cast x->bf16; [8192,9216) w1 transpose;
//             [9216,10240) w2 transpose.  All block-uniform branches.
__device__ __forceinline__ void transpose_tile(
    const float* __restrict__ in, bf16* __restrict__ out,
    int K, int N, int k0, int n0, int t, bf16 (*tile)[72])
{
    const int lr = t >> 4;          // 0..15
    const int lc = (t & 15) << 2;   // 0,4,..60
#pragma unroll
    for (int p = 0; p < 4; ++p) {
        int k = p * 16 + lr;
        float4 v = *(const float4*)(in + (size_t)(k0 + k) * N + n0 + lc);
        tile[lc + 0][k] = (bf16)v.x;
        tile[lc + 1][k] = (bf16)v.y;
        tile[lc + 2][k] = (bf16)v.z;
        tile[lc + 3][k] = (bf16)v.w;
    }
    __syncthreads();

    const int wr = t >> 3;          // 0..31
    const int wc = (t & 7) << 3;    // 0,8,..56
#pragma unroll
    for (int p = 0; p < 2; ++p) {
        int n = p * 32 + wr;
        *(bf16x8*)(out + (size_t)(n0 + n) * K + k0 + wc) =
            *(const bf16x8*)&tile[n][wc];
    }
}

__global__ __launch_bounds__(256) void prep_fused(
    const float* __restrict__ x,  bf16* __restrict__ xb,
    const float* __restrict__ w1, bf16* __restrict__ w1t,
    const float* __restrict__ w2, bf16* __restrict__ w2t)
{
    __shared__ __align__(16) bf16 tile[64][72];
    const int bid = blockIdx.x;
    const int t   = threadIdx.x;

    if (bid < 8192) {
        int i = bid * 256 + t;
        float4 v = ((const float4*)x)[i];
        bf16x4 o;
        o.x = (bf16)v.x; o.y = (bf16)v.y; o.z = (bf16)v.z; o.w = (bf16)v.w;
        ((bf16x4*)xb)[i] = o;
    } else if (bid < 9216) {
        int b = bid - 8192;
        transpose_tile(w1, w1t, 1024, 4096, (b >> 6) * 64, (b & 63) * 64, t, tile);
    } else {
        int b = bid - 9216;
        transpose_tile(w2, w2t, 4096, 1024, (b >> 4) * 64, (b & 15) * 64, t, tile);
    }
}

// ---------------------------------------------------------------------------
// GEMM1: C = relu(A @ Bt^T + bias), bf16 out.  Verified R2/R6 body:
// 128x128, BK=64, 256 thr, 16x16x32 MFMA, chunk-XOR swizzle (0 conflicts).
template <int FUSE_RELU_BF16>
__global__ __launch_bounds__(256, 3) void gemm_bt(
    const bf16* __restrict__ A, const bf16* __restrict__ Bt,
    const float* __restrict__ bias, void* __restrict__ Cout,
    int M, int N, int K)
{
    __shared__ __align__(16) bf16 As[BM * BK];
    __shared__ __align__(16) bf16 Bs[BN * BK];

    const int tid  = threadIdx.x;
    const int wave = tid >> 6;
    const int lane = tid & 63;

    const int l8  = lane >> 3;
    const int c8  = lane & 7;
    const int swc = (c8 ^ l8) << 3;
    const size_t K_ = (size_t)K;

    const bf16* gA[4]; const bf16* gB[4];
    bf16* lA[4]; bf16* lB[4];
#pragma unroll
    for (int g = 0; g < 4; ++g) {
        const int rr = wave * 32 + g * 8 + l8;
        gA[g] = A  + ((size_t)blockIdx.y * BM + rr) * K_ + swc;
        gB[g] = Bt + ((size_t)blockIdx.x * BN + rr) * K_ + swc;
        lA[g] = &As[(wave * 32 + g * 8) * BK] + lane * 8;
        lB[g] = &Bs[(wave * 32 + g * 8) * BK] + lane * 8;
    }

    const int wm   = (wave >> 1) << 6;
    const int wn   = (wave & 1) << 6;
    const int quad = lane >> 4;
    const int r    = lane & 15;
    const int r7   = lane & 7;

    f32x4 acc[4][4] = {};

    for (int k0 = 0; k0 < K; k0 += BK) {
        __syncthreads();
#pragma unroll
        for (int g = 0; g < 4; ++g) {
            gload_lds16(gA[g], lA[g]);
            gload_lds16(gB[g], lB[g]);
            gA[g] += BK; gB[g] += BK;
        }
        __syncthreads();

#pragma unroll
        for (int h = 0; h < 2; ++h) {
            const int ch = ((h * 4 + quad) ^ r7) << 3;
            bf16x8 af[4], bfr[4];
#pragma unroll
            for (int i = 0; i < 4; ++i)
                af[i] = *(const bf16x8*)&As[(wm + i * 16 + r) * BK + ch];
#pragma unroll
            for (int j = 0; j < 4; ++j)
                bfr[j] = *(const bf16x8*)&Bs[(wn + j * 16 + r) * BK + ch];
#pragma unroll
            for (int i = 0; i < 4; ++i)
#pragma unroll
                for (int j = 0; j < 4; ++j)
                    acc[i][j] = __builtin_amdgcn_mfma_f32_16x16x32_bf16(
                        af[i], bfr[j], acc[i][j], 0, 0, 0);
        }
    }

    const int m_base = blockIdx.y * BM + wm + quad * 4;
    const int n_base = blockIdx.x * BN + wn + r;
    float bv[4];
#pragma unroll
    for (int j = 0; j < 4; ++j) bv[j] = bias[n_base + j * 16];

    if (FUSE_RELU_BF16) {
        bf16* Cb = (bf16*)Cout;
#pragma unroll
        for (int i = 0; i < 4; ++i) {
#pragma unroll
            for (int p = 0; p < 4; ++p) {
                size_t row = (size_t)(m_base + i * 16 + p) * (size_t)N;
#pragma unroll
                for (int j = 0; j < 4; ++j) {
                    float v = acc[i][j][p] + bv[j];
                    v = v > 0.f ? v : 0.f;
                    Cb[row + n_base + j * 16] = (bf16)v;
                }
            }
        }
    } else {
        float* Cf = (float*)Cout;
#pragma unroll
        for (int i = 0; i < 4; ++i) {
#pragma unroll
            for (int p = 0; p < 4; ++p) {
                size_t row = (size_t)(m_base + i * 16 + p) * (size_t)N;
#pragma unroll
                for (int j = 0; j < 4; ++j) {
                    Cf[row + n_base + j * 16] = acc[i][j][p] + bv[j];
                }
            }
        }
    }
}

// ---------------------------------------------------------------------------
// GEMM2: out = A @ Bt^T + bias, f32 out.  Verified R9 body:
// 128x128 tile, BK=128, 256 thr, 32 K-iters, LDS 64 KiB (2 blocks/CU),
// 16-chunk XOR swizzle mask &15 (81.8 us, 0 conflicts).
__global__ __launch_bounds__(256, 2) void gemm_bt2_k128(
    const bf16* __restrict__ A, const bf16* __restrict__ Bt,
    const float* __restrict__ bias, float* __restrict__ Cf,
    int M, int N, int K)
{
    __shared__ __align__(16) bf16 As[128 * 128];   // 32 KiB
    __shared__ __align__(16) bf16 Bs[128 * 128];   // 32 KiB

    const int tid  = threadIdx.x;
    const int wave = tid >> 6;
    const int lane = tid & 63;

    const int sr   = tid >> 4;                     // 0..15
    const int swc  = ((tid & 15) ^ sr) << 3;       // elem offset of 16B chunk
    const size_t K_ = (size_t)K;

    const bf16* gA[8]; const bf16* gB[8];
    bf16* lA[8]; bf16* lB[8];
#pragma unroll
    for (int g = 0; g < 8; ++g) {
        const int rr = g * 16 + sr;
        gA[g] = A  + ((size_t)blockIdx.y * 128 + rr) * K_ + swc;
        gB[g] = Bt + ((size_t)blockIdx.x * 128 + rr) * K_ + swc;
        lA[g] = &As[(g * 16) * 128] + tid * 8;     // linear dest
        lB[g] = &Bs[(g * 16) * 128] + tid * 8;
    }

    const int wm   = (wave >> 1) << 6;
    const int wn   = (wave & 1) << 6;
    const int quad = lane >> 4;
    const int r    = lane & 15;

    f32x4 acc[4][4] = {};

    for (int k0 = 0; k0 < K; k0 += 128) {
        __syncthreads();
#pragma unroll
        for (int g = 0; g < 8; ++g) {
            gload_lds16(gA[g], lA[g]);
            gload_lds16(gB[g], lB[g]);
            gA[g] += 128; gB[g] += 128;
        }
        __syncthreads();

#pragma unroll
        for (int ks = 0; ks < 4; ++ks) {           // 4 k-sub-steps of 32
            bf16x8 af[4], bfr[4];
#pragma unroll
            for (int i = 0; i < 4; ++i) {
                const int row = wm + i * 16 + r;
                const int ch  = (((ks * 4 + quad) ^ (row & 15)) << 3);
                af[i] = *(const bf16x8*)&As[row * 128 + ch];
            }
#pragma unroll
            for (int j = 0; j < 4; ++j) {
                const int row = wn + j * 16 + r;
                const int ch  = (((ks * 4 + quad) ^ (row & 15)) << 3);
                bfr[j] = *(const bf16x8*)&Bs[row * 128 + ch];
            }
#pragma unroll
            for (int i = 0; i < 4; ++i)
#pragma unroll
                for (int j = 0; j < 4; ++j)
                    acc[i][j] = __builtin_amdgcn_mfma_f32_16x16x32_bf16(
                        af[i], bfr[j], acc[i][j], 0, 0, 0);
        }
    }

    const int m_base = blockIdx.y * 128 + wm + quad * 4;
    const int n_base = blockIdx.x * 128 + wn + r;
    float bv[4];
#pragma unroll
    for (int j = 0; j < 4; ++j) bv[j] = bias[n_base + j * 16];

#pragma unroll
    for (int i = 0; i < 4; ++i) {
#pragma unroll
        for (int p = 0; p < 4; ++p) {
            size_t row = (size_t)(m_base + i * 16 + p) * (size_t)N;
#pragma unroll
            for (int j = 0; j < 4; ++j) {
                Cf[row + n_base + j * 16] = acc[i][j][p] + bv[j];
            }
        }
    }
}

// ---------------------------------------------------------------------------
extern "C" void kernel_launch(void* const* d_in, const int* in_sizes, int n_in,
                              void* d_out, int out_size, void* d_ws, size_t ws_size,
                              hipStream_t stream)
{
    const float* x  = (const float*)d_in[0];  // [8192,1024]
    const float* w1 = (const float*)d_in[1];  // [1024,4096]
    const float* b1 = (const float*)d_in[2];  // [4096]
    const float* w2 = (const float*)d_in[3];  // [4096,1024]
    const float* b2 = (const float*)d_in[4];  // [1024]
    float* out = (float*)d_out;               // [8192,1024]

    const int M = 8192, D = 1024, W = 4096;

    char* ws = (char*)d_ws;
    bf16* xb  = (bf16*)(ws);                           // 16 MiB: [8192,1024]
    bf16* w1t = (bf16*)(ws + (size_t)(16 << 20));      //  8 MiB: [4096,1024]
    bf16* w2t = (bf16*)(ws + (size_t)(24 << 20));      //  8 MiB: [1024,4096]
    bf16* h   = (bf16*)(ws + (size_t)(32 << 20));      // 64 MiB: [8192,4096]

    // 1. fused prep: cast x + transpose w1 + transpose w2 (one launch)
    prep_fused<<<10240, 256, 0, stream>>>(x, xb, w1, w1t, w2, w2t);

    // 2. h = relu(xb @ w1 + b1), bf16  [M][W]   128x128 tile, BK=64
    gemm_bt<1><<<dim3(W / BN, M / BM), 256, 0, stream>>>(
        xb, w1t, b1, (void*)h, M, W, D);

    // 3. out = h @ w2 + b2, f32  [M][D]         128x128 tile, BK=128
    gemm_bt2_k128<<<dim3(D / 128, M / 128), 256, 0, stream>>>(
        h, w2t, b2, out, M, D, W);
}